// Round 4
// baseline (237.924 us; speedup 1.0000x reference)
//
#include <hip/hip_runtime.h>
#include <hip/hip_bf16.h>
#include <math.h>

// MHA: B=2,S=2048,E=1024,H=16,Dk=64. fp32 in/out, bf16 MFMA internally.
// cvt_w: 4 weights fp32->bf16 (one launch). cvt_x3: q/k/v fp32->bf16 (one launch).
// gemm_qkv: fused Q/K/V projections via grid.z=3, 64x128 tile (1536 blocks =
//   6/CU: TLP carries the single-buffered loop; measured best in r2), BK=64,
//   swizzled global_load_lds. QSCALE (0.125*log2e) folded into Q epilogue.
// gemm_out: 64x64 tile (1024 blocks = 4/CU), fp32 out + bias.
// attn: 32x32-MFMA flash, in-register P via cvt_pk + v_permlane32_swap_b32.
//   RING-4 K/V LDS with COUNTED vmcnt(8) + raw s_barrier (T3/T4): each staged
//   tile gets ~2 iterations of flight time -> global->LDS latency hidden.
//   setprio(1) around MFMA clusters (T5). No __syncthreads in the loop.

constexpr int Sn = 2048;
constexpr int En = 1024;
constexpr int Hn = 16;
constexpr int Dk = 64;
constexpr int Kn = 1024;
constexpr size_t WSZ = 1048576;   // 1024*1024
constexpr size_t TSZ = 4194304;   // 4096*1024

// 0.125 * log2(e): folded into Q so softmax is a bare v_exp_f32 (exp2).
#define QSCALE 0.18033688011112042f

typedef __bf16 bf16x8 __attribute__((ext_vector_type(8)));
typedef float  f32x4  __attribute__((ext_vector_type(4)));
typedef float  f32x16 __attribute__((ext_vector_type(16)));

union U16 { uint4 u; bf16x8 v; __hip_bfloat16 h[8]; };
union U8  { uint2 u; __hip_bfloat162 h2[2]; __hip_bfloat16 h[4]; };
union U4  { unsigned u; __hip_bfloat162 h2; };

__device__ inline U16 cvt8f(const float* __restrict__ p) {
    float4 a = *(const float4*)p;
    float4 b = *(const float4*)(p + 4);
    U16 r;
    r.h[0] = __float2bfloat16(a.x); r.h[1] = __float2bfloat16(a.y);
    r.h[2] = __float2bfloat16(a.z); r.h[3] = __float2bfloat16(a.w);
    r.h[4] = __float2bfloat16(b.x); r.h[5] = __float2bfloat16(b.y);
    r.h[6] = __float2bfloat16(b.z); r.h[7] = __float2bfloat16(b.w);
    return r;
}

__device__ inline void gload16(const __hip_bfloat16* g, __hip_bfloat16* l) {
    __builtin_amdgcn_global_load_lds(
        (const __attribute__((address_space(1))) void*)g,
        (__attribute__((address_space(3))) void*)l, 16, 0, 0);
}

// Stage ROWS x 64 bf16 tile via global_load_lds, XOR-swizzled:
// LDS granule p of row r holds global granule p^(r&7). Dest lane-contiguous.
// Issues ROWS/(8*NW) gload16 per wave (counted by the attn vmcnt schedule!).
template<int ROWS, int NW>
__device__ inline void stage_tile(const __hip_bfloat16* __restrict__ src, int ld,
                                  __hip_bfloat16* lds, int w, int lane) {
    int l8 = lane >> 3;
    int g = (lane & 7) ^ (l8 & 7);
    #pragma unroll
    for (int j = 0; j < ROWS / (8 * NW); ++j) {
        int c = j * NW + w;
        gload16(src + (size_t)(c * 8 + l8) * ld + g * 8, lds + c * 512);
    }
}

// ---------------- converts ----------------
__global__ __launch_bounds__(256)
void cvt_w(const float* __restrict__ w0, const float* __restrict__ w1,
           const float* __restrict__ w2, const float* __restrict__ w3,
           __hip_bfloat16* __restrict__ dst)
{
    int y = blockIdx.y;
    const float* src = (y == 0) ? w0 : (y == 1) ? w1 : (y == 2) ? w2 : w3;
    size_t i = ((size_t)blockIdx.x * 256 + threadIdx.x) * 8;
    U16 r = cvt8f(src + i);
    *(uint4*)&dst[(size_t)y * WSZ + i] = r.u;
}

__global__ __launch_bounds__(256)
void cvt_x3(const float* __restrict__ q, const float* __restrict__ k,
            const float* __restrict__ v, __hip_bfloat16* __restrict__ dst)
{
    int z = blockIdx.y;
    const float* src = (z == 0) ? q : (z == 1) ? k : v;
    size_t i = ((size_t)blockIdx.x * 256 + threadIdx.x) * 8;
    U16 r = cvt8f(src + i);
    *(uint4*)&dst[(size_t)z * TSZ + i] = r.u;
}

// ---------------- GEMM core: acc[m][n] += A[m][k]*W[n][k], BK=64 ----------------
// 64(M) x NT*32(N) tile, 4 waves each 32 x NT*16 (2 x NT frags).
// Single-buffered (measured best at this size: 6 blocks/CU TLP hides latency).
template<int NT>
__device__ inline void gemm_core(const __hip_bfloat16* __restrict__ Ab,
                                 const __hip_bfloat16* __restrict__ Wb,
                                 __hip_bfloat16* As, __hip_bfloat16* Bs,
                                 f32x4 (&acc)[2][NT], int w, int lane)
{
    const int l15 = lane & 15, lg = lane >> 4, l7 = lane & 7;
    const int wm = (w & 1) * 32, wn = (w >> 1) * (NT * 16);
    const int coff0 = (lg ^ l7) * 8;
    const int coff1 = ((4 + lg) ^ l7) * 8;

    #pragma unroll
    for (int i = 0; i < 2; ++i)
        #pragma unroll
        for (int j = 0; j < NT; ++j) acc[i][j] = {0.f, 0.f, 0.f, 0.f};

    for (int k0 = 0; k0 < Kn; k0 += 64) {
        stage_tile<64, 4>(Ab + k0, Kn, As, w, lane);
        stage_tile<NT * 32, 4>(Wb + k0, Kn, Bs, w, lane);
        __syncthreads();

        U16 af[2][2], bf[NT][2];
        #pragma unroll
        for (int mt = 0; mt < 2; ++mt) {
            int r = (wm + mt * 16 + l15) * 64;
            af[mt][0].u = *(const uint4*)&As[r + coff0];
            af[mt][1].u = *(const uint4*)&As[r + coff1];
        }
        #pragma unroll
        for (int nt = 0; nt < NT; ++nt) {
            int r = (wn + nt * 16 + l15) * 64;
            bf[nt][0].u = *(const uint4*)&Bs[r + coff0];
            bf[nt][1].u = *(const uint4*)&Bs[r + coff1];
        }
        #pragma unroll
        for (int mt = 0; mt < 2; ++mt)
            #pragma unroll
            for (int nt = 0; nt < NT; ++nt) {
                acc[mt][nt] = __builtin_amdgcn_mfma_f32_16x16x32_bf16(af[mt][0].v, bf[nt][0].v, acc[mt][nt], 0, 0, 0);
                acc[mt][nt] = __builtin_amdgcn_mfma_f32_16x16x32_bf16(af[mt][1].v, bf[nt][1].v, acc[mt][nt], 0, 0, 0);
            }
        __syncthreads();
    }
}

// ---------------- fused Q/K/V projection (grid.z = 0/1/2) ----------------
__global__ __launch_bounds__(256)
void gemm_qkv(const __hip_bfloat16* __restrict__ X, const __hip_bfloat16* __restrict__ Wall,
              const float* __restrict__ bq, const float* __restrict__ bk,
              const float* __restrict__ bv, __hip_bfloat16* __restrict__ outbase)
{
    __shared__ __align__(16) __hip_bfloat16 As[64 * 64];
    __shared__ __align__(16) __hip_bfloat16 Bs[128 * 64];

    const int tid = threadIdx.x, w = tid >> 6, lane = tid & 63;
    const int z = blockIdx.z;
    const int blockM = blockIdx.x * 64, blockN = blockIdx.y * 128;

    f32x4 acc[2][4];
    gemm_core<4>(X + (size_t)z * TSZ + (size_t)blockM * Kn,
                 Wall + (size_t)z * WSZ + (size_t)blockN * Kn,
                 As, Bs, acc, w, lane);

    const float scale = (z == 0) ? QSCALE : 1.0f;
    const float* bias = (z == 0) ? bq : (z == 1) ? bk : bv;
    __hip_bfloat16* out = outbase + (size_t)z * TSZ;

    const int l15 = lane & 15, lg = lane >> 4;
    const int wm = (w & 1) * 32, wn = (w >> 1) * 64;

    // C/D: col=l15, row=lg*4+i
    #pragma unroll
    for (int nt = 0; nt < 4; ++nt) {
        int n = blockN + wn + nt * 16 + l15;
        float bvn = bias[n] * scale;
        int h_ = n >> 6, d_ = n & 63;
        #pragma unroll
        for (int mt = 0; mt < 2; ++mt) {
            int m0 = blockM + wm + mt * 16 + lg * 4;
            int b_ = m0 >> 11, s_ = m0 & (Sn - 1);
            if (z < 2) {
                // [B][H][S][Dk]
                #pragma unroll
                for (int i = 0; i < 4; ++i)
                    out[(((size_t)b_ * Hn + h_) * Sn + s_ + i) * Dk + d_] =
                        __float2bfloat16(fmaf(acc[mt][nt][i], scale, bvn));
            } else {
                // [B][H][Dk][S]
                U8 pk;
                #pragma unroll
                for (int i = 0; i < 4; ++i)
                    pk.h[i] = __float2bfloat16(fmaf(acc[mt][nt][i], scale, bvn));
                *(uint2*)&out[(((size_t)b_ * Hn + h_) * Dk + d_) * Sn + s_] = pk.u;
            }
        }
    }
}

// ---------------- output projection: 64x64 tile, fp32 out + bias ----------------
__global__ __launch_bounds__(256)
void gemm_out(const __hip_bfloat16* __restrict__ A, const __hip_bfloat16* __restrict__ W,
              const float* __restrict__ bias, float* __restrict__ out)
{
    __shared__ __align__(16) __hip_bfloat16 As[64 * 64];
    __shared__ __align__(16) __hip_bfloat16 Bs[64 * 64];

    const int tid = threadIdx.x, w = tid >> 6, lane = tid & 63;
    const int blockM = blockIdx.x * 64, blockN = blockIdx.y * 64;

    f32x4 acc[2][2];
    gemm_core<2>(A + (size_t)blockM * Kn, W + (size_t)blockN * Kn,
                 As, Bs, acc, w, lane);

    const int l15 = lane & 15, lg = lane >> 4;
    const int wm = (w & 1) * 32, wn = (w >> 1) * 32;

    #pragma unroll
    for (int nt = 0; nt < 2; ++nt) {
        int n = blockN + wn + nt * 16 + l15;
        float bvn = bias[n];
        #pragma unroll
        for (int mt = 0; mt < 2; ++mt) {
            int m0 = blockM + wm + mt * 16 + lg * 4;
            #pragma unroll
            for (int i = 0; i < 4; ++i)
                out[(size_t)(m0 + i) * Kn + n] = acc[mt][nt][i] + bvn;
        }
    }
}

// ---------------- flash attention (32x32 MFMA, ring-4 counted-vmcnt) ----------
// 256 thr (4 waves), 128 q/block (32/wave), 64-key tiles.
// Q pre-scaled by 0.125*log2(e) -> p = exp2(s).
// Per wave per staged tile: 4 gload16 (K:2 + V:2). Ring-4 schedule:
//   prologue: stage 0,1,2 (12 outstanding).
//   iter t: vmcnt(8) [stage t landed, per-wave FIFO] -> s_barrier [all waves'
//   chunks landed] -> issue stage(t+3) into buf (t+3)&3 [last read iter t-1,
//   ordered by this barrier] -> compute buf t&3.
//   Tail: stages wrap to tiles 0..2 (dummy refills, keeps vmcnt immediate
//   uniform); explicit vmcnt(0) drain before epilogue so no LDS write
//   outlives the workgroup.
__global__ __launch_bounds__(256)
void attn(const __hip_bfloat16* __restrict__ Q, const __hip_bfloat16* __restrict__ K,
          const __hip_bfloat16* __restrict__ Vt, __hip_bfloat16* __restrict__ X)
{
    __shared__ __align__(16) __hip_bfloat16 Ks[4][64 * 64];
    __shared__ __align__(16) __hip_bfloat16 Vts[4][64 * 64];

    const int bh = blockIdx.y, q0 = blockIdx.x * 128;
    const int tid = threadIdx.x, w = tid >> 6, lane = tid & 63;
    const int l31 = lane & 31, hi = lane >> 5;

    const __hip_bfloat16* Qb = Q  + (size_t)bh * Sn * Dk;
    const __hip_bfloat16* Kb = K  + (size_t)bh * Sn * Dk;
    const __hip_bfloat16* Vb = Vt + (size_t)bh * Dk * Sn;

    // Q B-frags: qf[d0t]: lane = (col q = l31), d = d0t*16 + hi*8 + j
    U16 qf[4];
    {
        const __hip_bfloat16* qp = Qb + (size_t)(q0 + w * 32 + l31) * Dk + hi * 8;
        #pragma unroll
        for (int d0t = 0; d0t < 4; ++d0t)
            qf[d0t].u = *(const uint4*)(qp + d0t * 16);
    }
    // Drain Q loads NOW so manual vmcnt counting below is exact.
    asm volatile("s_waitcnt vmcnt(0)" ::: "memory");

    f32x16 o[2];
    #pragma unroll
    for (int dt = 0; dt < 2; ++dt)
        #pragma unroll
        for (int r = 0; r < 16; ++r) o[dt][r] = 0.f;
    float lpart = 0.f;

    // prologue: 3 tiles in flight (12 loads/wave)
    #pragma unroll
    for (int p = 0; p < 3; ++p) {
        stage_tile<64, 4>(Kb + (size_t)p * 64 * Dk, Dk, Ks[p], w, lane);
        stage_tile<64, 4>(Vb + p * 64, Sn, Vts[p], w, lane);
    }

    for (int t = 0; t < Sn / 64; ++t) {
        // stage t landed for this wave (12 outstanding -> 8 = stages t+1,t+2)
        asm volatile("s_waitcnt vmcnt(8)" ::: "memory");
        __builtin_amdgcn_s_barrier();          // all waves' chunks of stage t landed
        __builtin_amdgcn_sched_barrier(0);

        const int ts = (t + 3) & 31;           // wraps to 0..2 at tail (dummy)
        const int sb = (t + 3) & 3;
        stage_tile<64, 4>(Kb + (size_t)ts * 64 * Dk, Dk, Ks[sb], w, lane);
        stage_tile<64, 4>(Vb + ts * 64, Sn, Vts[sb], w, lane);

        const int cur = t & 3;

        // --- S^T = K·Q^T: 2 kt-tiles of 32 keys ---
        f32x16 st[2];
        #pragma unroll
        for (int kt = 0; kt < 2; ++kt)
            #pragma unroll
            for (int r = 0; r < 16; ++r) st[kt][r] = 0.f;

        __builtin_amdgcn_s_setprio(1);
        #pragma unroll
        for (int d0t = 0; d0t < 4; ++d0t) {
            #pragma unroll
            for (int kt = 0; kt < 2; ++kt) {
                int r = kt * 32 + l31;                       // K row
                int col = (((d0t * 2 + hi)) ^ (r & 7)) * 8;  // unswizzle granule
                U16 kf; kf.u = *(const uint4*)&Ks[cur][r * 64 + col];
                st[kt] = __builtin_amdgcn_mfma_f32_32x32x16_bf16(kf.v, qf[d0t].v, st[kt], 0, 0, 0);
            }
        }
        __builtin_amdgcn_s_setprio(0);

        // --- softmax + in-register P->A-frag redistribution ---
        uint4 pa[4];   // PV A-frags for k0 = 0,16,32,48
        #pragma unroll
        for (int kt = 0; kt < 2; ++kt) {
            float pv[16];
            #pragma unroll
            for (int r = 0; r < 16; ++r) pv[r] = __builtin_amdgcn_exp2f(st[kt][r]);
            float s01 = (pv[0] + pv[1]) + (pv[2] + pv[3]);
            float s23 = (pv[4] + pv[5]) + (pv[6] + pv[7]);
            float s45 = (pv[8] + pv[9]) + (pv[10] + pv[11]);
            float s67 = (pv[12] + pv[13]) + (pv[14] + pv[15]);
            lpart += (s01 + s23) + (s45 + s67);

            uint wv[8];
            #pragma unroll
            for (int m2 = 0; m2 < 8; ++m2) {
                U4 pk; pk.h2 = __float22bfloat162_rn({pv[2 * m2], pv[2 * m2 + 1]});
                wv[m2] = pk.u;
            }
            // swap(a,b): a' = {a_lo, b_lo_partner}, b' = {a_hi_partner, b_hi}
            asm volatile("v_permlane32_swap_b32 %0, %1" : "+v"(wv[0]), "+v"(wv[2]));
            asm volatile("v_permlane32_swap_b32 %0, %1" : "+v"(wv[1]), "+v"(wv[3]));
            asm volatile("v_permlane32_swap_b32 %0, %1" : "+v"(wv[4]), "+v"(wv[6]));
            asm volatile("v_permlane32_swap_b32 %0, %1" : "+v"(wv[5]), "+v"(wv[7]));
            pa[kt * 2 + 0] = make_uint4(wv[0], wv[1], wv[2], wv[3]);
            pa[kt * 2 + 1] = make_uint4(wv[4], wv[5], wv[6], wv[7]);
        }

        // --- PV: o[dt] += P(32q x 64k) · V(64k x 32d) ---
        __builtin_amdgcn_s_setprio(1);
        #pragma unroll
        for (int k0t = 0; k0t < 4; ++k0t) {
            U16 pau; pau.u = pa[k0t];
            #pragma unroll
            for (int dt = 0; dt < 2; ++dt) {
                int r = dt * 32 + l31;                       // V^T row = d
                int col = (((k0t * 2 + hi)) ^ (r & 7)) * 8;  // s-granule unswizzle
                U16 vf; vf.u = *(const uint4*)&Vts[cur][r * 64 + col];
                o[dt] = __builtin_amdgcn_mfma_f32_32x32x16_bf16(pau.v, vf.v, o[dt], 0, 0, 0);
            }
        }
        __builtin_amdgcn_s_setprio(0);
    }

    // drain dummy stages before LDS dealloc / epilogue
    asm volatile("s_waitcnt vmcnt(0)" ::: "memory");

    // --- epilogue: normalize + store (registers only) ---
    lpart += __shfl_xor(lpart, 32, 64);
    float linv = 1.f / lpart;

    float li[16];
    #pragma unroll
    for (int r = 0; r < 16; ++r) {
        int qr = (r & 3) + 8 * (r >> 2) + 4 * hi;
        li[r] = __shfl(linv, qr, 64);
    }

    int b_ = bh >> 4, h_ = bh & (Hn - 1);
    #pragma unroll
    for (int r = 0; r < 16; ++r) {
        int qr = (r & 3) + 8 * (r >> 2) + 4 * hi;
        int sr = q0 + w * 32 + qr;
        __hip_bfloat16* xp = X + ((size_t)(b_ * Sn + sr)) * En + h_ * Dk + l31;
        xp[0]  = __float2bfloat16(o[0][r] * li[r]);
        xp[32] = __float2bfloat16(o[1][r] * li[r]);
    }
}

extern "C" void kernel_launch(void* const* d_in, const int* in_sizes, int n_in,
                              void* d_out, int out_size, void* d_ws, size_t ws_size,
                              hipStream_t stream)
{
    const float* query = (const float*)d_in[0];
    const float* key   = (const float*)d_in[1];
    const float* value = (const float*)d_in[2];
    const float* Wq = (const float*)d_in[3];
    const float* bq = (const float*)d_in[4];
    const float* Wk = (const float*)d_in[5];
    const float* bk = (const float*)d_in[6];
    const float* Wv = (const float*)d_in[7];
    const float* bv = (const float*)d_in[8];
    const float* Wo = (const float*)d_in[9];
    const float* bo = (const float*)d_in[10];
    float* out = (float*)d_out;

    // ws (bf16 elems): xqkv[3*TSZ=24MB] | Wbf[4*WSZ=8MB] | QKV[3*TSZ=24MB] = 56MB.
    // Xw (attn out, 8MB) aliases xqkv[0] (dead after projections consume it).
    __hip_bfloat16* xqkv = (__hip_bfloat16*)d_ws;
    __hip_bfloat16* Wbf  = xqkv + 3 * TSZ;
    __hip_bfloat16* QKVw = Wbf + 4 * WSZ;
    __hip_bfloat16* Xw   = xqkv;

    cvt_w<<<dim3(512, 4), 256, 0, stream>>>(Wq, Wk, Wv, Wo, Wbf);
    cvt_x3<<<dim3(2048, 3), 256, 0, stream>>>(query, key, value, xqkv);
    gemm_qkv<<<dim3(64, 8, 3), 256, 0, stream>>>(xqkv, Wbf, bq, bk, bv, QKVw);
    attn<<<dim3(Sn / 128, 32), 256, 0, stream>>>(QKVw, QKVw + TSZ, QKVw + 2 * TSZ, Xw);
    gemm_out<<<dim3(64, 16), 256, 0, stream>>>(Xw, Wbf + 3 * WSZ, bo, out);
}

// Round 5
// 237.898 us; speedup vs baseline: 1.0001x; 1.0001x over previous
//
#include <hip/hip_runtime.h>
#include <hip/hip_bf16.h>
#include <math.h>

// MHA: B=2,S=2048,E=1024,H=16,Dk=64. fp32 in/out, bf16 MFMA internally.
// cvt_w: 4 weights fp32->bf16 (one launch). cvt_x3: q/k/v fp32->bf16 (one launch).
// gemm_qkv: fused Q/K/V projections via grid.z=3, 64x128 tile (1536 blocks =
//   6/CU), BK=64, swizzled global_load_lds. QSCALE folded into Q epilogue.
// gemm_out: 64x64 tile (1024 blocks = 4/CU), fp32 out + bias.
// attn: 32x32-MFMA flash, in-register P (cvt_pk + v_permlane32_swap_b32).
//   NEW: bh-major grid (XCD = bh%8 -> K/V L2-resident, 2MB/XCD) and 8-wave
//   blocks with kv-split: waves (qs=w&3) own 32-q sub-tiles, groups g=w>>2
//   compute alternating tiles (g=0 even/buf0, g=1 odd/buf1) -> 4 waves/SIMD.
//   No-max softmax is a pure sum -> exact O/l combine via LDS at the end
//   (overlays the dead K/V buffers).

constexpr int Sn = 2048;
constexpr int En = 1024;
constexpr int Hn = 16;
constexpr int Dk = 64;
constexpr int Kn = 1024;
constexpr size_t WSZ = 1048576;   // 1024*1024
constexpr size_t TSZ = 4194304;   // 4096*1024

// 0.125 * log2(e): folded into Q so softmax is a bare v_exp_f32 (exp2).
#define QSCALE 0.18033688011112042f

typedef __bf16 bf16x8 __attribute__((ext_vector_type(8)));
typedef float  f32x4  __attribute__((ext_vector_type(4)));
typedef float  f32x16 __attribute__((ext_vector_type(16)));

union U16 { uint4 u; bf16x8 v; __hip_bfloat16 h[8]; };
union U8  { uint2 u; __hip_bfloat162 h2[2]; __hip_bfloat16 h[4]; };
union U4  { unsigned u; __hip_bfloat162 h2; };

__device__ inline U16 cvt8f(const float* __restrict__ p) {
    float4 a = *(const float4*)p;
    float4 b = *(const float4*)(p + 4);
    U16 r;
    r.h[0] = __float2bfloat16(a.x); r.h[1] = __float2bfloat16(a.y);
    r.h[2] = __float2bfloat16(a.z); r.h[3] = __float2bfloat16(a.w);
    r.h[4] = __float2bfloat16(b.x); r.h[5] = __float2bfloat16(b.y);
    r.h[6] = __float2bfloat16(b.z); r.h[7] = __float2bfloat16(b.w);
    return r;
}

__device__ inline void gload16(const __hip_bfloat16* g, __hip_bfloat16* l) {
    __builtin_amdgcn_global_load_lds(
        (const __attribute__((address_space(1))) void*)g,
        (__attribute__((address_space(3))) void*)l, 16, 0, 0);
}

// Stage ROWS x 64 bf16 tile via global_load_lds, XOR-swizzled:
// LDS granule p of row r holds global granule p^(r&7). Dest lane-contiguous.
template<int ROWS, int NW>
__device__ inline void stage_tile(const __hip_bfloat16* __restrict__ src, int ld,
                                  __hip_bfloat16* lds, int w, int lane) {
    int l8 = lane >> 3;
    int g = (lane & 7) ^ (l8 & 7);
    #pragma unroll
    for (int j = 0; j < ROWS / (8 * NW); ++j) {
        int c = j * NW + w;
        gload16(src + (size_t)(c * 8 + l8) * ld + g * 8, lds + c * 512);
    }
}

// ---------------- converts ----------------
__global__ __launch_bounds__(256)
void cvt_w(const float* __restrict__ w0, const float* __restrict__ w1,
           const float* __restrict__ w2, const float* __restrict__ w3,
           __hip_bfloat16* __restrict__ dst)
{
    int y = blockIdx.y;
    const float* src = (y == 0) ? w0 : (y == 1) ? w1 : (y == 2) ? w2 : w3;
    size_t i = ((size_t)blockIdx.x * 256 + threadIdx.x) * 8;
    U16 r = cvt8f(src + i);
    *(uint4*)&dst[(size_t)y * WSZ + i] = r.u;
}

__global__ __launch_bounds__(256)
void cvt_x3(const float* __restrict__ q, const float* __restrict__ k,
            const float* __restrict__ v, __hip_bfloat16* __restrict__ dst)
{
    int z = blockIdx.y;
    const float* src = (z == 0) ? q : (z == 1) ? k : v;
    size_t i = ((size_t)blockIdx.x * 256 + threadIdx.x) * 8;
    U16 r = cvt8f(src + i);
    *(uint4*)&dst[(size_t)z * TSZ + i] = r.u;
}

// ---------------- GEMM core: acc[m][n] += A[m][k]*W[n][k], BK=64 ----------------
// 64(M) x NT*32(N) tile, 4 waves each 32 x NT*16 (2 x NT frags).
// Single-buffered (measured best at this size: 6 blocks/CU TLP hides latency).
template<int NT>
__device__ inline void gemm_core(const __hip_bfloat16* __restrict__ Ab,
                                 const __hip_bfloat16* __restrict__ Wb,
                                 __hip_bfloat16* As, __hip_bfloat16* Bs,
                                 f32x4 (&acc)[2][NT], int w, int lane)
{
    const int l15 = lane & 15, lg = lane >> 4, l7 = lane & 7;
    const int wm = (w & 1) * 32, wn = (w >> 1) * (NT * 16);
    const int coff0 = (lg ^ l7) * 8;
    const int coff1 = ((4 + lg) ^ l7) * 8;

    #pragma unroll
    for (int i = 0; i < 2; ++i)
        #pragma unroll
        for (int j = 0; j < NT; ++j) acc[i][j] = {0.f, 0.f, 0.f, 0.f};

    for (int k0 = 0; k0 < Kn; k0 += 64) {
        stage_tile<64, 4>(Ab + k0, Kn, As, w, lane);
        stage_tile<NT * 32, 4>(Wb + k0, Kn, Bs, w, lane);
        __syncthreads();

        U16 af[2][2], bf[NT][2];
        #pragma unroll
        for (int mt = 0; mt < 2; ++mt) {
            int r = (wm + mt * 16 + l15) * 64;
            af[mt][0].u = *(const uint4*)&As[r + coff0];
            af[mt][1].u = *(const uint4*)&As[r + coff1];
        }
        #pragma unroll
        for (int nt = 0; nt < NT; ++nt) {
            int r = (wn + nt * 16 + l15) * 64;
            bf[nt][0].u = *(const uint4*)&Bs[r + coff0];
            bf[nt][1].u = *(const uint4*)&Bs[r + coff1];
        }
        #pragma unroll
        for (int mt = 0; mt < 2; ++mt)
            #pragma unroll
            for (int nt = 0; nt < NT; ++nt) {
                acc[mt][nt] = __builtin_amdgcn_mfma_f32_16x16x32_bf16(af[mt][0].v, bf[nt][0].v, acc[mt][nt], 0, 0, 0);
                acc[mt][nt] = __builtin_amdgcn_mfma_f32_16x16x32_bf16(af[mt][1].v, bf[nt][1].v, acc[mt][nt], 0, 0, 0);
            }
        __syncthreads();
    }
}

// ---------------- fused Q/K/V projection (grid.z = 0/1/2) ----------------
__global__ __launch_bounds__(256)
void gemm_qkv(const __hip_bfloat16* __restrict__ X, const __hip_bfloat16* __restrict__ Wall,
              const float* __restrict__ bq, const float* __restrict__ bk,
              const float* __restrict__ bv, __hip_bfloat16* __restrict__ outbase)
{
    __shared__ __align__(16) __hip_bfloat16 As[64 * 64];
    __shared__ __align__(16) __hip_bfloat16 Bs[128 * 64];

    const int tid = threadIdx.x, w = tid >> 6, lane = tid & 63;
    const int z = blockIdx.z;
    const int blockM = blockIdx.x * 64, blockN = blockIdx.y * 128;

    f32x4 acc[2][4];
    gemm_core<4>(X + (size_t)z * TSZ + (size_t)blockM * Kn,
                 Wall + (size_t)z * WSZ + (size_t)blockN * Kn,
                 As, Bs, acc, w, lane);

    const float scale = (z == 0) ? QSCALE : 1.0f;
    const float* bias = (z == 0) ? bq : (z == 1) ? bk : bv;
    __hip_bfloat16* out = outbase + (size_t)z * TSZ;

    const int l15 = lane & 15, lg = lane >> 4;
    const int wm = (w & 1) * 32, wn = (w >> 1) * 64;

    // C/D: col=l15, row=lg*4+i
    #pragma unroll
    for (int nt = 0; nt < 4; ++nt) {
        int n = blockN + wn + nt * 16 + l15;
        float bvn = bias[n] * scale;
        int h_ = n >> 6, d_ = n & 63;
        #pragma unroll
        for (int mt = 0; mt < 2; ++mt) {
            int m0 = blockM + wm + mt * 16 + lg * 4;
            int b_ = m0 >> 11, s_ = m0 & (Sn - 1);
            if (z < 2) {
                // [B][H][S][Dk]
                #pragma unroll
                for (int i = 0; i < 4; ++i)
                    out[(((size_t)b_ * Hn + h_) * Sn + s_ + i) * Dk + d_] =
                        __float2bfloat16(fmaf(acc[mt][nt][i], scale, bvn));
            } else {
                // [B][H][Dk][S]
                U8 pk;
                #pragma unroll
                for (int i = 0; i < 4; ++i)
                    pk.h[i] = __float2bfloat16(fmaf(acc[mt][nt][i], scale, bvn));
                *(uint2*)&out[(((size_t)b_ * Hn + h_) * Dk + d_) * Sn + s_] = pk.u;
            }
        }
    }
}

// ---------------- output projection: 64x64 tile, fp32 out + bias ----------------
__global__ __launch_bounds__(256)
void gemm_out(const __hip_bfloat16* __restrict__ A, const __hip_bfloat16* __restrict__ W,
              const float* __restrict__ bias, float* __restrict__ out)
{
    __shared__ __align__(16) __hip_bfloat16 As[64 * 64];
    __shared__ __align__(16) __hip_bfloat16 Bs[64 * 64];

    const int tid = threadIdx.x, w = tid >> 6, lane = tid & 63;
    const int blockM = blockIdx.x * 64, blockN = blockIdx.y * 64;

    f32x4 acc[2][2];
    gemm_core<2>(A + (size_t)blockM * Kn, W + (size_t)blockN * Kn,
                 As, Bs, acc, w, lane);

    const int l15 = lane & 15, lg = lane >> 4;
    const int wm = (w & 1) * 32, wn = (w >> 1) * 32;

    #pragma unroll
    for (int nt = 0; nt < 2; ++nt) {
        int n = blockN + wn + nt * 16 + l15;
        float bvn = bias[n];
        #pragma unroll
        for (int mt = 0; mt < 2; ++mt) {
            int m0 = blockM + wm + mt * 16 + lg * 4;
            #pragma unroll
            for (int i = 0; i < 4; ++i)
                out[(size_t)(m0 + i) * Kn + n] = acc[mt][nt][i] + bvn;
        }
    }
}

// ---------------- flash attention (32x32 MFMA, 8-wave kv-split) ----------------
// grid (32 bh, 16 qx): XCD = bh%8 -> each XCD serves 4 bh -> K/V (2MB) L2-resident.
// 512 thr = 8 waves: qs = w&3 owns q-sub (32 rows of the 128-q tile);
// g = w>>2 computes tiles t with t&1==g (g=0 -> buf0, g=1 -> buf1).
// All waves cooperatively stage (1 gload16/wave per K and V tile).
// No-max softmax (Q pre-scaled by 0.125*log2e -> p=exp2(s)) is a pure sum, so
// the g-groups' O/l partials combine EXACTLY by addition through LDS at the end.
__global__ __launch_bounds__(512)
void attn(const __hip_bfloat16* __restrict__ Q, const __hip_bfloat16* __restrict__ K,
          const __hip_bfloat16* __restrict__ Vt, __hip_bfloat16* __restrict__ X)
{
    __shared__ __align__(16) __hip_bfloat16 KVs[2][2][64 * 64];  // [buf][0=K,1=Vt]
    __shared__ float Lc[4][64];

    const int bh = blockIdx.x, q0 = blockIdx.y * 128;
    const int tid = threadIdx.x, w = tid >> 6, lane = tid & 63;
    const int qs = w & 3, g = w >> 2;
    const int l31 = lane & 31, hi = lane >> 5;

    const __hip_bfloat16* Qb = Q  + (size_t)bh * Sn * Dk;
    const __hip_bfloat16* Kb = K  + (size_t)bh * Sn * Dk;
    const __hip_bfloat16* Vb = Vt + (size_t)bh * Dk * Sn;

    // Q B-frags: qf[d0t]: lane = (col q = l31), d = d0t*16 + hi*8 + j
    U16 qf[4];
    {
        const __hip_bfloat16* qp = Qb + (size_t)(q0 + qs * 32 + l31) * Dk + hi * 8;
        #pragma unroll
        for (int d0t = 0; d0t < 4; ++d0t)
            qf[d0t].u = *(const uint4*)(qp + d0t * 16);
    }

    f32x16 o[2];
    #pragma unroll
    for (int dt = 0; dt < 2; ++dt)
        #pragma unroll
        for (int r = 0; r < 16; ++r) o[dt][r] = 0.f;
    float lpart = 0.f;

    stage_tile<64, 8>(Kb, Dk, KVs[0][0], w, lane);
    stage_tile<64, 8>(Vb, Sn, KVs[0][1], w, lane);

    for (int t = 0; t < Sn / 64; ++t) {
        __syncthreads();   // tile t's loads drained; prior reads of buf cur^1 done
        const int cur = t & 1;
        if (t + 1 < Sn / 64) {
            stage_tile<64, 8>(Kb + (size_t)(t + 1) * 64 * Dk, Dk, KVs[cur ^ 1][0], w, lane);
            stage_tile<64, 8>(Vb + (t + 1) * 64, Sn, KVs[cur ^ 1][1], w, lane);
        }
        if (cur != g) continue;   // wave-uniform: this group computes alternate tiles

        const __hip_bfloat16* Ksc = KVs[cur][0];
        const __hip_bfloat16* Vsc = KVs[cur][1];

        // --- S^T = K·Q^T: 2 kt-tiles of 32 keys ---
        f32x16 st[2];
        #pragma unroll
        for (int kt = 0; kt < 2; ++kt)
            #pragma unroll
            for (int r = 0; r < 16; ++r) st[kt][r] = 0.f;

        #pragma unroll
        for (int d0t = 0; d0t < 4; ++d0t) {
            #pragma unroll
            for (int kt = 0; kt < 2; ++kt) {
                int r = kt * 32 + l31;                       // K row
                int col = (((d0t * 2 + hi)) ^ (r & 7)) * 8;  // unswizzle granule
                U16 kf; kf.u = *(const uint4*)&Ksc[r * 64 + col];
                st[kt] = __builtin_amdgcn_mfma_f32_32x32x16_bf16(kf.v, qf[d0t].v, st[kt], 0, 0, 0);
            }
        }

        // --- softmax + in-register P->A-frag redistribution ---
        uint4 pa[4];   // PV A-frags for k0 = 0,16,32,48
        #pragma unroll
        for (int kt = 0; kt < 2; ++kt) {
            float pv[16];
            #pragma unroll
            for (int r = 0; r < 16; ++r) pv[r] = __builtin_amdgcn_exp2f(st[kt][r]);
            float s01 = (pv[0] + pv[1]) + (pv[2] + pv[3]);
            float s23 = (pv[4] + pv[5]) + (pv[6] + pv[7]);
            float s45 = (pv[8] + pv[9]) + (pv[10] + pv[11]);
            float s67 = (pv[12] + pv[13]) + (pv[14] + pv[15]);
            lpart += (s01 + s23) + (s45 + s67);

            uint wv[8];
            #pragma unroll
            for (int m2 = 0; m2 < 8; ++m2) {
                U4 pk; pk.h2 = __float22bfloat162_rn({pv[2 * m2], pv[2 * m2 + 1]});
                wv[m2] = pk.u;
            }
            // swap(a,b): a' = {a_lo, b_lo_partner}, b' = {a_hi_partner, b_hi}
            asm volatile("v_permlane32_swap_b32 %0, %1" : "+v"(wv[0]), "+v"(wv[2]));
            asm volatile("v_permlane32_swap_b32 %0, %1" : "+v"(wv[1]), "+v"(wv[3]));
            asm volatile("v_permlane32_swap_b32 %0, %1" : "+v"(wv[4]), "+v"(wv[6]));
            asm volatile("v_permlane32_swap_b32 %0, %1" : "+v"(wv[5]), "+v"(wv[7]));
            pa[kt * 2 + 0] = make_uint4(wv[0], wv[1], wv[2], wv[3]);
            pa[kt * 2 + 1] = make_uint4(wv[4], wv[5], wv[6], wv[7]);
        }

        // --- PV: o[dt] += P(32q x 64k) · V(64k x 32d) ---
        #pragma unroll
        for (int k0t = 0; k0t < 4; ++k0t) {
            U16 pau; pau.u = pa[k0t];
            #pragma unroll
            for (int dt = 0; dt < 2; ++dt) {
                int r = dt * 32 + l31;                       // V^T row = d
                int col = (((k0t * 2 + hi)) ^ (r & 7)) * 8;  // s-granule unswizzle
                U16 vf; vf.u = *(const uint4*)&Vsc[r * 64 + col];
                o[dt] = __builtin_amdgcn_mfma_f32_32x32x16_bf16(pau.v, vf.v, o[dt], 0, 0, 0);
            }
        }
    }

    // --- combine the two kv-groups (exact: pure sums) ---
    __syncthreads();                       // all reads of KVs done
    float* Ocomb = (float*)KVs;            // 8192 floats = 4 qs x 32 q x 64 d
    if (g == 0) {
        #pragma unroll
        for (int dt = 0; dt < 2; ++dt)
            #pragma unroll
            for (int r = 0; r < 16; ++r) {
                int qr = (r & 3) + 8 * (r >> 2) + 4 * hi;
                Ocomb[(qs * 32 + qr) * 64 + dt * 32 + l31] = o[dt][r];
            }
        Lc[qs][lane] = lpart;
    }
    __syncthreads();
    if (g == 1) {
        #pragma unroll
        for (int dt = 0; dt < 2; ++dt)
            #pragma unroll
            for (int r = 0; r < 16; ++r) {
                int qr = (r & 3) + 8 * (r >> 2) + 4 * hi;
                o[dt][r] += Ocomb[(qs * 32 + qr) * 64 + dt * 32 + l31];
            }
        lpart += Lc[qs][lane];
        lpart += __shfl_xor(lpart, 32, 64);
        float linv = 1.f / lpart;

        float li[16];
        #pragma unroll
        for (int r = 0; r < 16; ++r) {
            int qr = (r & 3) + 8 * (r >> 2) + 4 * hi;
            li[r] = __shfl(linv, qr, 64);
        }

        int b_ = bh >> 4, h_ = bh & (Hn - 1);
        #pragma unroll
        for (int r = 0; r < 16; ++r) {
            int qr = (r & 3) + 8 * (r >> 2) + 4 * hi;
            int sr = q0 + qs * 32 + qr;
            __hip_bfloat16* xp = X + ((size_t)(b_ * Sn + sr)) * En + h_ * Dk + l31;
            xp[0]  = __float2bfloat16(o[0][r] * li[r]);
            xp[32] = __float2bfloat16(o[1][r] * li[r]);
        }
    }
}

extern "C" void kernel_launch(void* const* d_in, const int* in_sizes, int n_in,
                              void* d_out, int out_size, void* d_ws, size_t ws_size,
                              hipStream_t stream)
{
    const float* query = (const float*)d_in[0];
    const float* key   = (const float*)d_in[1];
    const float* value = (const float*)d_in[2];
    const float* Wq = (const float*)d_in[3];
    const float* bq = (const float*)d_in[4];
    const float* Wk = (const float*)d_in[5];
    const float* bk = (const float*)d_in[6];
    const float* Wv = (const float*)d_in[7];
    const float* bv = (const float*)d_in[8];
    const float* Wo = (const float*)d_in[9];
    const float* bo = (const float*)d_in[10];
    float* out = (float*)d_out;

    // ws (bf16 elems): xqkv[3*TSZ=24MB] | Wbf[4*WSZ=8MB] | QKV[3*TSZ=24MB] = 56MB.
    // Xw (attn out, 8MB) aliases xqkv[0] (dead after projections consume it).
    __hip_bfloat16* xqkv = (__hip_bfloat16*)d_ws;
    __hip_bfloat16* Wbf  = xqkv + 3 * TSZ;
    __hip_bfloat16* QKVw = Wbf + 4 * WSZ;
    __hip_bfloat16* Xw   = xqkv;

    cvt_w<<<dim3(512, 4), 256, 0, stream>>>(Wq, Wk, Wv, Wo, Wbf);
    cvt_x3<<<dim3(2048, 3), 256, 0, stream>>>(query, key, value, xqkv);
    gemm_qkv<<<dim3(64, 8, 3), 256, 0, stream>>>(xqkv, Wbf, bq, bk, bv, QKVw);
    attn<<<dim3(32, Sn / 128), 512, 0, stream>>>(QKVw, QKVw + TSZ, QKVw + 2 * TSZ, Xw);
    gemm_out<<<dim3(64, 16), 256, 0, stream>>>(Xw, Wbf + 3 * WSZ, bo, out);
}

// Round 6
// 227.825 us; speedup vs baseline: 1.0443x; 1.0442x over previous
//
#include <hip/hip_runtime.h>
#include <hip/hip_bf16.h>
#include <math.h>

// MHA: B=2,S=2048,E=1024,H=16,Dk=64. fp32 in/out, bf16 MFMA internally.
// cvt_all: all 7 fp32->bf16 converts in one launch (8192 blocks).
// gemm_qkv: fused Q/K/V projections via grid.z=3, 64x128 tile (1536 blocks =
//   6/CU), BK=64, swizzled global_load_lds. QSCALE folded into Q epilogue.
// gemm_out: 64x64 tile (1024 blocks = 4/CU), fp32 out + bias.
// attn: 32x32-MFMA flash, in-register P (cvt_pk + v_permlane32_swap_b32).
//   bh-major grid (XCD=bh%8 -> K/V L2-resident; r5: FETCH 69.7->12.3MB).
//   64 q/block, 4 waves = (qs, kh): qs owns 32 q-rows, kh owns a 32-key half
//   of EVERY tile (no barrier-serialized groups). 1024 blocks = 4/CU =
//   4 waves/SIMD (attn is VALU-issue-bound; r3 had only 2). Per-wave VALU
//   halved; loop unrolled x2 so LDS addresses are loop-invariant.
//   Exact f32 combine of the kh-halves through dead K-LDS at the end.

constexpr int Sn = 2048;
constexpr int En = 1024;
constexpr int Hn = 16;
constexpr int Dk = 64;
constexpr int Kn = 1024;
constexpr size_t WSZ = 1048576;   // 1024*1024
constexpr size_t TSZ = 4194304;   // 4096*1024

// 0.125 * log2(e): folded into Q so softmax is a bare v_exp_f32 (exp2).
#define QSCALE 0.18033688011112042f

typedef __bf16 bf16x8 __attribute__((ext_vector_type(8)));
typedef float  f32x4  __attribute__((ext_vector_type(4)));
typedef float  f32x16 __attribute__((ext_vector_type(16)));

union U16 { uint4 u; bf16x8 v; __hip_bfloat16 h[8]; };
union U8  { uint2 u; __hip_bfloat162 h2[2]; __hip_bfloat16 h[4]; };
union U4  { unsigned u; __hip_bfloat162 h2; };

__device__ inline U16 cvt8f(const float* __restrict__ p) {
    float4 a = *(const float4*)p;
    float4 b = *(const float4*)(p + 4);
    U16 r;
    r.h[0] = __float2bfloat16(a.x); r.h[1] = __float2bfloat16(a.y);
    r.h[2] = __float2bfloat16(a.z); r.h[3] = __float2bfloat16(a.w);
    r.h[4] = __float2bfloat16(b.x); r.h[5] = __float2bfloat16(b.y);
    r.h[6] = __float2bfloat16(b.z); r.h[7] = __float2bfloat16(b.w);
    return r;
}

__device__ inline void gload16(const __hip_bfloat16* g, __hip_bfloat16* l) {
    __builtin_amdgcn_global_load_lds(
        (const __attribute__((address_space(1))) void*)g,
        (__attribute__((address_space(3))) void*)l, 16, 0, 0);
}

// Stage ROWS x 64 bf16 tile via global_load_lds, XOR-swizzled:
// LDS granule p of row r holds global granule p^(r&7). Dest lane-contiguous.
template<int ROWS, int NW>
__device__ inline void stage_tile(const __hip_bfloat16* __restrict__ src, int ld,
                                  __hip_bfloat16* lds, int w, int lane) {
    int l8 = lane >> 3;
    int g = (lane & 7) ^ (l8 & 7);
    #pragma unroll
    for (int j = 0; j < ROWS / (8 * NW); ++j) {
        int c = j * NW + w;
        gload16(src + (size_t)(c * 8 + l8) * ld + g * 8, lds + c * 512);
    }
}

// ---------------- converts (single launch) ----------------
// blocks 0..6143: q/k/v (2048 each) -> xdst. blocks 6144..8191: 4 weights (512 each).
__global__ __launch_bounds__(256)
void cvt_all(const float* __restrict__ q, const float* __restrict__ k,
             const float* __restrict__ v,
             const float* __restrict__ w0, const float* __restrict__ w1,
             const float* __restrict__ w2, const float* __restrict__ w3,
             __hip_bfloat16* __restrict__ xdst, __hip_bfloat16* __restrict__ wdst)
{
    int bx = blockIdx.x;
    const float* src;
    __hip_bfloat16* dst;
    size_t base;
    if (bx < 6144) {
        int z = bx >> 11;
        src = (z == 0) ? q : (z == 1) ? k : v;
        dst = xdst + (size_t)z * TSZ;
        base = ((size_t)(bx & 2047) * 256 + threadIdx.x) * 8;
    } else {
        int y = (bx - 6144) >> 9;
        src = (y == 0) ? w0 : (y == 1) ? w1 : (y == 2) ? w2 : w3;
        dst = wdst + (size_t)y * WSZ;
        base = ((size_t)((bx - 6144) & 511) * 256 + threadIdx.x) * 8;
    }
    U16 r = cvt8f(src + base);
    *(uint4*)&dst[base] = r.u;
}

// ---------------- GEMM core: acc[m][n] += A[m][k]*W[n][k], BK=64 ----------------
// 64(M) x NT*32(N) tile, 4 waves each 32 x NT*16 (2 x NT frags).
// Single-buffered (measured best at this size: 6 blocks/CU TLP hides latency).
template<int NT>
__device__ inline void gemm_core(const __hip_bfloat16* __restrict__ Ab,
                                 const __hip_bfloat16* __restrict__ Wb,
                                 __hip_bfloat16* As, __hip_bfloat16* Bs,
                                 f32x4 (&acc)[2][NT], int w, int lane)
{
    const int l15 = lane & 15, lg = lane >> 4, l7 = lane & 7;
    const int wm = (w & 1) * 32, wn = (w >> 1) * (NT * 16);
    const int coff0 = (lg ^ l7) * 8;
    const int coff1 = ((4 + lg) ^ l7) * 8;

    #pragma unroll
    for (int i = 0; i < 2; ++i)
        #pragma unroll
        for (int j = 0; j < NT; ++j) acc[i][j] = {0.f, 0.f, 0.f, 0.f};

    for (int k0 = 0; k0 < Kn; k0 += 64) {
        stage_tile<64, 4>(Ab + k0, Kn, As, w, lane);
        stage_tile<NT * 32, 4>(Wb + k0, Kn, Bs, w, lane);
        __syncthreads();

        U16 af[2][2], bf[NT][2];
        #pragma unroll
        for (int mt = 0; mt < 2; ++mt) {
            int r = (wm + mt * 16 + l15) * 64;
            af[mt][0].u = *(const uint4*)&As[r + coff0];
            af[mt][1].u = *(const uint4*)&As[r + coff1];
        }
        #pragma unroll
        for (int nt = 0; nt < NT; ++nt) {
            int r = (wn + nt * 16 + l15) * 64;
            bf[nt][0].u = *(const uint4*)&Bs[r + coff0];
            bf[nt][1].u = *(const uint4*)&Bs[r + coff1];
        }
        #pragma unroll
        for (int mt = 0; mt < 2; ++mt)
            #pragma unroll
            for (int nt = 0; nt < NT; ++nt) {
                acc[mt][nt] = __builtin_amdgcn_mfma_f32_16x16x32_bf16(af[mt][0].v, bf[nt][0].v, acc[mt][nt], 0, 0, 0);
                acc[mt][nt] = __builtin_amdgcn_mfma_f32_16x16x32_bf16(af[mt][1].v, bf[nt][1].v, acc[mt][nt], 0, 0, 0);
            }
        __syncthreads();
    }
}

// ---------------- fused Q/K/V projection (grid.z = 0/1/2) ----------------
__global__ __launch_bounds__(256)
void gemm_qkv(const __hip_bfloat16* __restrict__ X, const __hip_bfloat16* __restrict__ Wall,
              const float* __restrict__ bq, const float* __restrict__ bk,
              const float* __restrict__ bv, __hip_bfloat16* __restrict__ outbase)
{
    __shared__ __align__(16) __hip_bfloat16 As[64 * 64];
    __shared__ __align__(16) __hip_bfloat16 Bs[128 * 64];

    const int tid = threadIdx.x, w = tid >> 6, lane = tid & 63;
    const int z = blockIdx.z;
    const int blockM = blockIdx.x * 64, blockN = blockIdx.y * 128;

    f32x4 acc[2][4];
    gemm_core<4>(X + (size_t)z * TSZ + (size_t)blockM * Kn,
                 Wall + (size_t)z * WSZ + (size_t)blockN * Kn,
                 As, Bs, acc, w, lane);

    const float scale = (z == 0) ? QSCALE : 1.0f;
    const float* bias = (z == 0) ? bq : (z == 1) ? bk : bv;
    __hip_bfloat16* out = outbase + (size_t)z * TSZ;

    const int l15 = lane & 15, lg = lane >> 4;
    const int wm = (w & 1) * 32, wn = (w >> 1) * 64;

    // C/D: col=l15, row=lg*4+i
    #pragma unroll
    for (int nt = 0; nt < 4; ++nt) {
        int n = blockN + wn + nt * 16 + l15;
        float bvn = bias[n] * scale;
        int h_ = n >> 6, d_ = n & 63;
        #pragma unroll
        for (int mt = 0; mt < 2; ++mt) {
            int m0 = blockM + wm + mt * 16 + lg * 4;
            int b_ = m0 >> 11, s_ = m0 & (Sn - 1);
            if (z < 2) {
                // [B][H][S][Dk]
                #pragma unroll
                for (int i = 0; i < 4; ++i)
                    out[(((size_t)b_ * Hn + h_) * Sn + s_ + i) * Dk + d_] =
                        __float2bfloat16(fmaf(acc[mt][nt][i], scale, bvn));
            } else {
                // [B][H][Dk][S]
                U8 pk;
                #pragma unroll
                for (int i = 0; i < 4; ++i)
                    pk.h[i] = __float2bfloat16(fmaf(acc[mt][nt][i], scale, bvn));
                *(uint2*)&out[(((size_t)b_ * Hn + h_) * Dk + d_) * Sn + s_] = pk.u;
            }
        }
    }
}

// ---------------- output projection: 64x64 tile, fp32 out + bias ----------------
__global__ __launch_bounds__(256)
void gemm_out(const __hip_bfloat16* __restrict__ A, const __hip_bfloat16* __restrict__ W,
              const float* __restrict__ bias, float* __restrict__ out)
{
    __shared__ __align__(16) __hip_bfloat16 As[64 * 64];
    __shared__ __align__(16) __hip_bfloat16 Bs[64 * 64];

    const int tid = threadIdx.x, w = tid >> 6, lane = tid & 63;
    const int blockM = blockIdx.x * 64, blockN = blockIdx.y * 64;

    f32x4 acc[2][2];
    gemm_core<2>(A + (size_t)blockM * Kn, W + (size_t)blockN * Kn,
                 As, Bs, acc, w, lane);

    const int l15 = lane & 15, lg = lane >> 4;
    const int wm = (w & 1) * 32, wn = (w >> 1) * 32;

    #pragma unroll
    for (int nt = 0; nt < 2; ++nt) {
        int n = blockN + wn + nt * 16 + l15;
        float bvn = bias[n];
        #pragma unroll
        for (int mt = 0; mt < 2; ++mt) {
            int m0 = blockM + wm + mt * 16 + lg * 4;
            #pragma unroll
            for (int i = 0; i < 4; ++i)
                out[(size_t)(m0 + i) * Kn + n] = acc[mt][nt][i] + bvn;
        }
    }
}

// ---------------- flash attention (32x32 MFMA, 4 waves = qs x kh) ----------------
// grid (32 bh, 32 qx): XCD = bh%8 -> K/V L2-resident (measured r5).
// 256 thr, 4 waves: qs = w>>1 owns q-rows [q0+qs*32, +32); kh = w&1 owns the
// 32-key half of EVERY 64-key tile. All waves compute all iterations.
// S^T = mfma(K,Q): lane holds P[q=l31][k rows kh*32 + (reg&3)+8*(reg>>2)+4*hi].
// cvt_pk + 2x2 v_permlane32_swap_b32 -> PV A-frags in-register (no P LDS).
// No-max softmax (Q pre-scaled by 0.125*log2e -> p=exp2(s)): pure sums, so the
// two kh-halves combine EXACTLY by f32 addition through dead K-LDS at the end.
__global__ __launch_bounds__(256)
void attn(const __hip_bfloat16* __restrict__ Q, const __hip_bfloat16* __restrict__ K,
          const __hip_bfloat16* __restrict__ Vt, __hip_bfloat16* __restrict__ X)
{
    __shared__ __align__(16) __hip_bfloat16 Ks[2][64 * 64];
    __shared__ __align__(16) __hip_bfloat16 Vts[2][64 * 64];
    __shared__ float Lc[2][64];

    const int bh = blockIdx.x, q0 = blockIdx.y * 64;
    const int tid = threadIdx.x, w = tid >> 6, lane = tid & 63;
    const int qs = w >> 1, kh = w & 1;
    const int l31 = lane & 31, hi = lane >> 5;

    const __hip_bfloat16* Qb = Q  + (size_t)bh * Sn * Dk;
    const __hip_bfloat16* Kb = K  + (size_t)bh * Sn * Dk;
    const __hip_bfloat16* Vb = Vt + (size_t)bh * Dk * Sn;

    // Q B-frags: qf[d0t]: lane = (col q = l31), d = d0t*16 + hi*8 + j
    U16 qf[4];
    {
        const __hip_bfloat16* qp = Qb + (size_t)(q0 + qs * 32 + l31) * Dk + hi * 8;
        #pragma unroll
        for (int d0t = 0; d0t < 4; ++d0t)
            qf[d0t].u = *(const uint4*)(qp + d0t * 16);
    }

    f32x16 o[2];
    #pragma unroll
    for (int dt = 0; dt < 2; ++dt)
        #pragma unroll
        for (int r = 0; r < 16; ++r) o[dt][r] = 0.f;
    float lpart = 0.f;

    const int rK = kh * 32 + l31;   // this wave's K row (loop-invariant)

    stage_tile<64, 4>(Kb, Dk, Ks[0], w, lane);
    stage_tile<64, 4>(Vb, Sn, Vts[0], w, lane);

    // body(cur, tn): barrier; prefetch tile tn into buf cur^1; compute buf cur.
    auto body = [&](int cur, int tn) {
        __syncthreads();
        if (tn < Sn / 64) {
            stage_tile<64, 4>(Kb + (size_t)tn * 64 * Dk, Dk, Ks[cur ^ 1], w, lane);
            stage_tile<64, 4>(Vb + tn * 64, Sn, Vts[cur ^ 1], w, lane);
        }

        // --- S^T = K·Q^T: this wave's 32-key half ---
        f32x16 st;
        #pragma unroll
        for (int r = 0; r < 16; ++r) st[r] = 0.f;
        #pragma unroll
        for (int d0t = 0; d0t < 4; ++d0t) {
            int col = ((d0t * 2 + hi) ^ (rK & 7)) * 8;   // loop-invariant
            U16 kf; kf.u = *(const uint4*)&Ks[cur][rK * 64 + col];
            st = __builtin_amdgcn_mfma_f32_32x32x16_bf16(kf.v, qf[d0t].v, st, 0, 0, 0);
        }

        // --- softmax + in-register P->A-frag redistribution ---
        float pv[16];
        #pragma unroll
        for (int r = 0; r < 16; ++r) pv[r] = __builtin_amdgcn_exp2f(st[r]);
        float s01 = (pv[0] + pv[1]) + (pv[2] + pv[3]);
        float s23 = (pv[4] + pv[5]) + (pv[6] + pv[7]);
        float s45 = (pv[8] + pv[9]) + (pv[10] + pv[11]);
        float s67 = (pv[12] + pv[13]) + (pv[14] + pv[15]);
        lpart += (s01 + s23) + (s45 + s67);

        uint wv[8];
        #pragma unroll
        for (int m2 = 0; m2 < 8; ++m2) {
            U4 pk; pk.h2 = __float22bfloat162_rn({pv[2 * m2], pv[2 * m2 + 1]});
            wv[m2] = pk.u;
        }
        // swap(a,b): a' = {a_lo, b_lo_partner}, b' = {a_hi_partner, b_hi}
        asm volatile("v_permlane32_swap_b32 %0, %1" : "+v"(wv[0]), "+v"(wv[2]));
        asm volatile("v_permlane32_swap_b32 %0, %1" : "+v"(wv[1]), "+v"(wv[3]));
        asm volatile("v_permlane32_swap_b32 %0, %1" : "+v"(wv[4]), "+v"(wv[6]));
        asm volatile("v_permlane32_swap_b32 %0, %1" : "+v"(wv[5]), "+v"(wv[7]));
        uint4 pa0 = make_uint4(wv[0], wv[1], wv[2], wv[3]);
        uint4 pa1 = make_uint4(wv[4], wv[5], wv[6], wv[7]);

        // --- PV: o[dt] += P(32q x 32k_half) · V(32k_half x 64d) ---
        #pragma unroll
        for (int j = 0; j < 2; ++j) {
            U16 pau; pau.u = (j == 0) ? pa0 : pa1;
            int k0t = kh * 2 + j;
            #pragma unroll
            for (int dt = 0; dt < 2; ++dt) {
                int rV = dt * 32 + l31;                       // V^T row = d
                int col = ((k0t * 2 + hi) ^ (rV & 7)) * 8;    // loop-invariant
                U16 vf; vf.u = *(const uint4*)&Vts[cur][rV * 64 + col];
                o[dt] = __builtin_amdgcn_mfma_f32_32x32x16_bf16(pau.v, vf.v, o[dt], 0, 0, 0);
            }
        }
    };

    for (int t = 0; t < Sn / 64; t += 2) {
        body(0, t + 1);
        body(1, t + 2);
    }

    // --- combine the two kh-halves (exact: pure sums) ---
    __syncthreads();                       // all reads of K/V LDS done
    float* Ocomb = (float*)Ks;             // 2 qs x 32 q x 64 d f32 = 16 KB
    if (kh == 0) {
        #pragma unroll
        for (int dt = 0; dt < 2; ++dt)
            #pragma unroll
            for (int r = 0; r < 16; ++r) {
                int qr = (r & 3) + 8 * (r >> 2) + 4 * hi;
                Ocomb[(qs * 32 + qr) * 64 + dt * 32 + l31] = o[dt][r];
            }
        Lc[qs][lane] = lpart;
    }
    __syncthreads();
    if (kh == 1) {
        #pragma unroll
        for (int dt = 0; dt < 2; ++dt)
            #pragma unroll
            for (int r = 0; r < 16; ++r) {
                int qr = (r & 3) + 8 * (r >> 2) + 4 * hi;
                o[dt][r] += Ocomb[(qs * 32 + qr) * 64 + dt * 32 + l31];
            }
        lpart += Lc[qs][lane];
        lpart += __shfl_xor(lpart, 32, 64);   // join hi-halves: full sum for q=l31
        float linv = 1.f / lpart;

        float li[16];
        #pragma unroll
        for (int r = 0; r < 16; ++r) {
            int qr = (r & 3) + 8 * (r >> 2) + 4 * hi;
            li[r] = __shfl(linv, qr, 64);
        }

        int b_ = bh >> 4, h_ = bh & (Hn - 1);
        #pragma unroll
        for (int r = 0; r < 16; ++r) {
            int qr = (r & 3) + 8 * (r >> 2) + 4 * hi;
            int sr = q0 + qs * 32 + qr;
            __hip_bfloat16* xp = X + ((size_t)(b_ * Sn + sr)) * En + h_ * Dk + l31;
            xp[0]  = __float2bfloat16(o[0][r] * li[r]);
            xp[32] = __float2bfloat16(o[1][r] * li[r]);
        }
    }
}

extern "C" void kernel_launch(void* const* d_in, const int* in_sizes, int n_in,
                              void* d_out, int out_size, void* d_ws, size_t ws_size,
                              hipStream_t stream)
{
    const float* query = (const float*)d_in[0];
    const float* key   = (const float*)d_in[1];
    const float* value = (const float*)d_in[2];
    const float* Wq = (const float*)d_in[3];
    const float* bq = (const float*)d_in[4];
    const float* Wk = (const float*)d_in[5];
    const float* bk = (const float*)d_in[6];
    const float* Wv = (const float*)d_in[7];
    const float* bv = (const float*)d_in[8];
    const float* Wo = (const float*)d_in[9];
    const float* bo = (const float*)d_in[10];
    float* out = (float*)d_out;

    // ws (bf16 elems): xqkv[3*TSZ=24MB] | Wbf[4*WSZ=8MB] | QKV[3*TSZ=24MB] = 56MB.
    // Xw (attn out, 8MB) aliases xqkv[0] (dead after projections consume it).
    __hip_bfloat16* xqkv = (__hip_bfloat16*)d_ws;
    __hip_bfloat16* Wbf  = xqkv + 3 * TSZ;
    __hip_bfloat16* QKVw = Wbf + 4 * WSZ;
    __hip_bfloat16* Xw   = xqkv;

    cvt_all<<<8192, 256, 0, stream>>>(query, key, value, Wq, Wk, Wv, Wo, xqkv, Wbf);
    gemm_qkv<<<dim3(64, 8, 3), 256, 0, stream>>>(xqkv, Wbf, bq, bk, bv, QKVw);
    attn<<<dim3(32, Sn / 64), 256, 0, stream>>>(QKVw, QKVw + TSZ, QKVw + 2 * TSZ, Xw);
    gemm_out<<<dim3(64, 16), 256, 0, stream>>>(Xw, Wbf + 3 * WSZ, bo, out);
}